// Round 7
// baseline (225.122 us; speedup 1.0000x reference)
//
#include <hip/hip_runtime.h>
#include <math.h>

// GCNConv forward with spectral-norm weight scaling, CSR-gather formulation.
// x[N,128] f32, edge_index[2,E] int, W[128,64] f32, bias[64] f32,
// ew[E] f32, u[128] f32  ->  out[N,64] f32.   N=100000, E=600000.
//
// Pipeline (deterministic):
//   memset packed[N]=0
//   edge_prep    : 4 edges/thread; ONE u64 atomic/edge:
//                  packed[col] += (1<<40)|fix32(sigmoid); slot[e] = old>>40
//   gemm_mfma    : xps = bf16( (x @ W) * rsqrt(deg_row+1) )   [raw W, bf16 MFMA,
//                  fp32 acc; sigma via linearity in gather epilogue]
//   scan_a       : per-1024-block exclusive scan of counts -> pos, btot
//   scan_b_sigma : single block: scan btot -> bexcl AND inv_sigma power-iter
//   permute      : spk[pos[col]+bexcl[col>>10]+slot[e]] = (row, w)   [seq only]
//   gather       : wave/node: out = isg*dis_n*(sum xps[row]*w + xps[n]) + bias

#define IN_DIM 128
#define OUT_DIM 64

#define FIXSHIFT 4294967296.0   // 2^32
#define CNTSHIFT 40
#define DEGMASK  ((1ull << CNTSHIFT) - 1)

typedef __attribute__((ext_vector_type(4))) short s16x4;
typedef __attribute__((ext_vector_type(8))) short s16x8;
typedef __attribute__((ext_vector_type(4))) float f32x4;

__device__ __forceinline__ short f2bf(float f) {
    unsigned int u = __float_as_uint(f);
    u = u + 0x7FFFu + ((u >> 16) & 1u);   // RNE
    return (short)(u >> 16);
}
__device__ __forceinline__ float bf2f(unsigned short s) {
    return __uint_as_float((unsigned int)s << 16);
}

// ---------------------------------------------------------------------------
// edge_prep: 4 edges/thread, 4 independent u64 atomics in flight.
// ---------------------------------------------------------------------------
__global__ __launch_bounds__(256) void edge_prep(const int* __restrict__ ei,
                                                 const float* __restrict__ ew,
                                                 unsigned long long* __restrict__ packed,
                                                 int* __restrict__ slot,
                                                 int E) {
    const int base = blockIdx.x * 1024 + threadIdx.x;
    int cols[4];
    unsigned long long incs[4];
    #pragma unroll
    for (int k = 0; k < 4; ++k) {
        const int e = base + k * 256;
        if (e < E) {
            const float w = 1.f / (1.f + expf(-ew[e]));
            cols[k] = ei[E + e];
            incs[k] = (1ull << CNTSHIFT) |
                      (unsigned long long)((double)w * FIXSHIFT);
        } else {
            cols[k] = -1;
        }
    }
    #pragma unroll
    for (int k = 0; k < 4; ++k) {
        const int e = base + k * 256;
        if (cols[k] >= 0) {
            const unsigned long long old = atomicAdd(&packed[cols[k]], incs[k]);
            slot[e] = (int)(old >> CNTSHIFT);
        }
    }
}

// ---------------------------------------------------------------------------
// gemm_mfma: xps = bf16((x @ W) * dis_row), bf16 MFMA 16x16x32.
// Block = 256 thr = 4 waves; 64 rows/block.
// ---------------------------------------------------------------------------
#define APITCH 136   // 128 + 8 bf16 pad

__global__ __launch_bounds__(256) void gemm_mfma(const float* __restrict__ x,
                                                 const float* __restrict__ W,
                                                 const unsigned long long* __restrict__ packed,
                                                 unsigned short* __restrict__ xps,
                                                 int N) {
    __shared__ short As[64 * APITCH];
    __shared__ short Wt[64 * APITCH];

    const int t = threadIdx.x;
    const int r0 = blockIdx.x * 64;

    // --- stage x rows -> bf16 LDS ---
    {
        const int rl = t >> 2;          // 0..63 local row
        const int q  = t & 3;           // k-quarter (32 floats)
        const int grow = min(r0 + rl, N - 1);
        const float4* src = (const float4*)(x + (size_t)grow * IN_DIM + q * 32);
        short* dst = &As[rl * APITCH + q * 32];
        #pragma unroll
        for (int i = 0; i < 8; ++i) {
            const float4 v = src[i];
            s16x4 s4;
            s4.x = f2bf(v.x); s4.y = f2bf(v.y);
            s4.z = f2bf(v.z); s4.w = f2bf(v.w);
            *(s16x4*)(dst + i * 4) = s4;
        }
    }
    // --- stage W transposed -> Wt[n][k] bf16 ---
    {
        #pragma unroll
        for (int p = 0; p < 2; ++p) {
            const int k  = p * 64 + (t >> 2);
            const int n0 = (t & 3) * 16;
            const float4* wsrc = (const float4*)(W + (size_t)k * OUT_DIM + n0);
            #pragma unroll
            for (int i = 0; i < 4; ++i) {
                const float4 v = wsrc[i];
                Wt[(n0 + 4 * i + 0) * APITCH + k] = f2bf(v.x);
                Wt[(n0 + 4 * i + 1) * APITCH + k] = f2bf(v.y);
                Wt[(n0 + 4 * i + 2) * APITCH + k] = f2bf(v.z);
                Wt[(n0 + 4 * i + 3) * APITCH + k] = f2bf(v.w);
            }
        }
    }
    __syncthreads();

    const int wave = t >> 6;
    const int lane = t & 63;
    const int m    = lane & 15;
    const int quad = lane >> 4;

    f32x4 acc[4];
    #pragma unroll
    for (int ct = 0; ct < 4; ++ct) acc[ct] = (f32x4){0.f, 0.f, 0.f, 0.f};

    const short* Abase = &As[(wave * 16 + m) * APITCH + quad * 8];
    const short* Bbase = &Wt[m * APITCH + quad * 8];

    #pragma unroll
    for (int kc = 0; kc < 4; ++kc) {
        const s16x8 a = *(const s16x8*)(Abase + kc * 32);
        #pragma unroll
        for (int ct = 0; ct < 4; ++ct) {
            const s16x8 b = *(const s16x8*)(Bbase + ct * 16 * APITCH + kc * 32);
            acc[ct] = __builtin_amdgcn_mfma_f32_16x16x32_bf16(a, b, acc[ct], 0, 0, 0);
        }
    }

    // C/D layout: col = lane&15, row = quad*4 + reg. Scale row by dis_row.
    #pragma unroll
    for (int r = 0; r < 4; ++r) {
        const int grow = r0 + wave * 16 + quad * 4 + r;
        const int gc = min(grow, N - 1);
        const unsigned long long p = packed[gc];
        const float deg = (float)((double)(p & DEGMASK) * (1.0 / FIXSHIFT));
        const float dis = rsqrtf(deg + 1.f);
        if (grow < N) {
            #pragma unroll
            for (int ct = 0; ct < 4; ++ct)
                xps[(size_t)grow * OUT_DIM + ct * 16 + m] =
                    (unsigned short)f2bf(acc[ct][r] * dis);
        }
    }
}

// ---------------------------------------------------------------------------
// scan_a: per-block (1024 items) exclusive scan of counts.
// ---------------------------------------------------------------------------
__global__ __launch_bounds__(256) void scan_a(const unsigned long long* __restrict__ packed,
                                              int* __restrict__ pos,
                                              int* __restrict__ btot,
                                              int N) {
    __shared__ int s[256];
    const int t = threadIdx.x;
    const int i0 = blockIdx.x * 1024 + t * 4;
    int v[4]; int sum = 0;
    #pragma unroll
    for (int j = 0; j < 4; ++j) {
        unsigned long long p = (i0 + j < N) ? packed[i0 + j] : 0ull;
        v[j] = (int)(p >> CNTSHIFT);
        sum += v[j];
    }
    s[t] = sum;
    __syncthreads();
    for (int off = 1; off < 256; off <<= 1) {
        int add = (t >= off) ? s[t - off] : 0;
        __syncthreads();
        s[t] += add;
        __syncthreads();
    }
    int excl = s[t] - sum;
    #pragma unroll
    for (int j = 0; j < 4; ++j) {
        if (i0 + j < N) pos[i0 + j] = excl;
        excl += v[j];
    }
    if (t == 255) btot[blockIdx.x] = s[255];
}

// ---------------------------------------------------------------------------
// scan_b_sigma: single block. Scan btot -> bexcl AND compute inv_sigma.
// ---------------------------------------------------------------------------
__global__ __launch_bounds__(256) void scan_b_sigma(const int* __restrict__ btot,
                                                    const float* __restrict__ W,
                                                    const float* __restrict__ u,
                                                    int* __restrict__ bexcl,
                                                    float* __restrict__ inv_sigma,
                                                    int NB) {
    __shared__ int s[256];
    __shared__ float red[256];
    __shared__ float vsh[OUT_DIM];
    const int t = threadIdx.x;

    const int own = (t < NB) ? btot[t] : 0;
    s[t] = own;
    __syncthreads();
    for (int off = 1; off < 256; off <<= 1) {
        int add = (t >= off) ? s[t - off] : 0;
        __syncthreads();
        s[t] += add;
        __syncthreads();
    }
    if (t < NB) bexcl[t] = s[t] - own;

    {
        const int j = t & 63;
        const int i0 = (t >> 6) * 32;
        float tv = 0.f;
        #pragma unroll 8
        for (int i = 0; i < 32; ++i) tv += W[(i0 + i) * OUT_DIM + j] * u[i0 + i];
        red[t] = tv;
    }
    __syncthreads();
    float tvj = 0.f;
    if (t < 64) tvj = red[t] + red[t + 64] + red[t + 128] + red[t + 192];
    __syncthreads();
    red[t] = (t < 64) ? tvj * tvj : 0.f;
    __syncthreads();
    for (int sr = 128; sr > 0; sr >>= 1) {
        if (t < sr) red[t] += red[t + sr];
        __syncthreads();
    }
    const float nv = sqrtf(red[0]) + 1e-12f;
    __syncthreads();
    if (t < 64) vsh[t] = tvj / nv;
    __syncthreads();
    float wv = 0.f;
    if (t < 128) {
        #pragma unroll 8
        for (int j = 0; j < OUT_DIM; ++j) wv += W[t * OUT_DIM + j] * vsh[j];
    }
    red[t] = (t < 128) ? wv * wv : 0.f;
    __syncthreads();
    for (int sr = 128; sr > 0; sr >>= 1) {
        if (t < sr) red[t] += red[t + sr];
        __syncthreads();
    }
    if (t == 0) {
        const float s2 = red[0];
        const float sn = sqrtf(s2);
        inv_sigma[0] = (sn + 1e-12f) / s2;   // 1/sigma
    }
}

// ---------------------------------------------------------------------------
// permute: spk[p] = (row, w). Sequential streams only; 2 edges/thread.
// ---------------------------------------------------------------------------
__global__ __launch_bounds__(256) void permute(const int* __restrict__ ei,
                                               const float* __restrict__ ew,
                                               const int* __restrict__ pos,
                                               const int* __restrict__ bexcl,
                                               const int* __restrict__ slot,
                                               int2* __restrict__ spk,
                                               int E) {
    const int base = blockIdx.x * 512 + threadIdx.x;
    #pragma unroll
    for (int k = 0; k < 2; ++k) {
        const int e = base + k * 256;
        if (e < E) {
            const int row = ei[e];
            const int col = ei[E + e];
            const float w = 1.f / (1.f + expf(-ew[e]));
            const int p = pos[col] + bexcl[col >> 10] + slot[e];
            int2 pk; pk.x = row; pk.y = __float_as_int(w);
            spk[p] = pk;
        }
    }
}

// ---------------------------------------------------------------------------
// gather: one wave per node, lane = column. bf16 xps rows (128 B/edge).
// out = isg * dis_n * (sum_e xps[row]*w + xps[n]) + bias
// ---------------------------------------------------------------------------
__global__ __launch_bounds__(256) void gather(const int2* __restrict__ spk,
                                              const int* __restrict__ pos,
                                              const int* __restrict__ bexcl,
                                              const unsigned long long* __restrict__ packed,
                                              const unsigned short* __restrict__ xps,
                                              const float* __restrict__ bias,
                                              const float* __restrict__ inv_sigma,
                                              float* __restrict__ out,
                                              int N) {
    const int t = threadIdx.x;
    const int wv = t >> 6;
    const int lane = t & 63;
    const int n = blockIdx.x * 4 + wv;
    if (n >= N) return;

    const unsigned long long p = packed[n];
    const int c = (int)(p >> CNTSHIFT);
    const float deg = (float)((double)(p & DEGMASK) * (1.0 / FIXSHIFT));
    const int st = pos[n] + bexcl[n >> 10];
    const int end = st + c;

    float acc0 = 0.f, acc1 = 0.f;
    int j = st;
    for (; j + 1 < end; j += 2) {
        const int2 p0 = spk[j];
        const int2 p1 = spk[j + 1];
        const float a0 = bf2f(xps[(size_t)p0.x * OUT_DIM + lane]);
        const float a1 = bf2f(xps[(size_t)p1.x * OUT_DIM + lane]);
        acc0 += a0 * __int_as_float(p0.y);
        acc1 += a1 * __int_as_float(p1.y);
    }
    if (j < end) {
        const int2 pk = spk[j];
        acc0 += bf2f(xps[(size_t)pk.x * OUT_DIM + lane]) * __int_as_float(pk.y);
    }

    const float self = bf2f(xps[(size_t)n * OUT_DIM + lane]);
    const float isg = inv_sigma[0];
    const float dis_n = rsqrtf(deg + 1.f);
    out[(size_t)n * OUT_DIM + lane] =
        isg * dis_n * (acc0 + acc1 + self) + bias[lane];
}

// ---------------------------------------------------------------------------
extern "C" void kernel_launch(void* const* d_in, const int* in_sizes, int n_in,
                              void* d_out, int out_size, void* d_ws, size_t ws_size,
                              hipStream_t stream) {
    const float* x    = (const float*)d_in[0];
    const int*   ei   = (const int*)d_in[1];
    const float* W    = (const float*)d_in[2];
    const float* bias = (const float*)d_in[3];
    const float* ew   = (const float*)d_in[4];
    const float* u    = (const float*)d_in[5];
    float* out = (float*)d_out;

    const int N = in_sizes[0] / IN_DIM;   // 100000
    const int E = in_sizes[4];            // 600000
    const int NB = (N + 1023) / 1024;     // 98 scan blocks (<=256)

    char* ws = (char*)d_ws;
    size_t off = 0;
    unsigned long long* packed = (unsigned long long*)(ws + off); off += (size_t)N * 8;
    int*   slot = (int*)  (ws + off); off += (size_t)E * 4;
    int*   pos  = (int*)  (ws + off); off += (size_t)N * 4;
    int*   btot = (int*)  (ws + off); off += 4096;
    int*   bexcl= (int*)  (ws + off); off += 4096;
    float* isg  = (float*)(ws + off); off += 1024;
    int2*  spk  = (int2*) (ws + off); off += (size_t)E * 8;
    unsigned short* xps = (unsigned short*)(ws + off); off += (size_t)N * OUT_DIM * 2;

    hipMemsetAsync(packed, 0, (size_t)N * 8, stream);
    edge_prep<<<(E + 1023) / 1024, 256, 0, stream>>>(ei, ew, packed, slot, E);
    gemm_mfma<<<(N + 63) / 64, 256, 0, stream>>>(x, W, packed, xps, N);
    scan_a<<<NB, 256, 0, stream>>>(packed, pos, btot, N);
    scan_b_sigma<<<1, 256, 0, stream>>>(btot, W, u, bexcl, isg, NB);
    permute<<<(E + 511) / 512, 256, 0, stream>>>(ei, ew, pos, bexcl, slot, spk, E);
    gather<<<(N + 3) / 4, 256, 0, stream>>>(spk, pos, bexcl, packed, xps, bias, isg, out, N);
}

// Round 8
// 190.594 us; speedup vs baseline: 1.1812x; 1.1812x over previous
//
#include <hip/hip_runtime.h>
#include <math.h>

// GCNConv forward with spectral-norm weight scaling, CSR-gather formulation.
// x[N,128] f32, edge_index[2,E] int, W[128,64] f32, bias[64] f32,
// ew[E] f32, u[128] f32  ->  out[N,64] f32.   N=100000, E=600000.
//
// Pipeline (deterministic):
//   memset packed[N]=0
//   edge_prep    : 1 edge/thread; ONE u64 atomic/edge:
//                  packed[col] += (1<<40)|fix32(sigmoid); slot[e] = old>>40
//   gemm_mfma    : xps = bf16( (x @ W) * rsqrt(deg_row+1) )   [raw W, bf16 MFMA,
//                  fp32 acc; sigma applied via linearity in gather epilogue]
//   scan_a       : per-1024-block exclusive scan of counts -> pos, btot
//   scan_b_sigma : single block: scan btot -> bexcl AND inv_sigma power-iter
//   permute      : spk[pos[col]+bexcl[col>>10]+slot[e]] = (row, w)
//   gather       : HALF-WAVE per node (lane = 2 cols via uint load), 2 nodes
//                  per wave, 4-way unrolled segment loop for MLP:
//                  out = isg*dis_n*(sum xps[row]*w + xps[n]) + bias

#define IN_DIM 128
#define OUT_DIM 64

#define FIXSHIFT 4294967296.0   // 2^32
#define CNTSHIFT 40
#define DEGMASK  ((1ull << CNTSHIFT) - 1)

typedef __attribute__((ext_vector_type(4))) short s16x4;
typedef __attribute__((ext_vector_type(8))) short s16x8;
typedef __attribute__((ext_vector_type(4))) float f32x4;

__device__ __forceinline__ short f2bf(float f) {
    unsigned int u = __float_as_uint(f);
    u = u + 0x7FFFu + ((u >> 16) & 1u);   // RNE
    return (short)(u >> 16);
}
// low/high bf16 halves of a uint -> float
__device__ __forceinline__ float bfLo(unsigned int u) {
    return __uint_as_float(u << 16);
}
__device__ __forceinline__ float bfHi(unsigned int u) {
    return __uint_as_float(u & 0xFFFF0000u);
}

// ---------------------------------------------------------------------------
// edge_prep: single packed 64-bit atomic per edge. 1 edge/thread (best-measured).
// ---------------------------------------------------------------------------
__global__ __launch_bounds__(256) void edge_prep(const int* __restrict__ ei,
                                                 const float* __restrict__ ew,
                                                 unsigned long long* __restrict__ packed,
                                                 int* __restrict__ slot,
                                                 int E) {
    const int e = blockIdx.x * 256 + threadIdx.x;
    if (e >= E) return;
    const float w = 1.f / (1.f + expf(-ew[e]));
    const int col = ei[E + e];
    const unsigned long long inc =
        (1ull << CNTSHIFT) | (unsigned long long)((double)w * FIXSHIFT);
    const unsigned long long old = atomicAdd(&packed[col], inc);
    slot[e] = (int)(old >> CNTSHIFT);
}

// ---------------------------------------------------------------------------
// gemm_mfma: xps = bf16((x @ W) * dis_row), bf16 MFMA 16x16x32.
// Block = 256 thr = 4 waves; 64 rows/block.
// ---------------------------------------------------------------------------
#define APITCH 136   // 128 + 8 bf16 pad

__global__ __launch_bounds__(256) void gemm_mfma(const float* __restrict__ x,
                                                 const float* __restrict__ W,
                                                 const unsigned long long* __restrict__ packed,
                                                 unsigned short* __restrict__ xps,
                                                 int N) {
    __shared__ short As[64 * APITCH];
    __shared__ short Wt[64 * APITCH];

    const int t = threadIdx.x;
    const int r0 = blockIdx.x * 64;

    // --- stage x rows -> bf16 LDS ---
    {
        const int rl = t >> 2;          // 0..63 local row
        const int q  = t & 3;           // k-quarter (32 floats)
        const int grow = min(r0 + rl, N - 1);
        const float4* src = (const float4*)(x + (size_t)grow * IN_DIM + q * 32);
        short* dst = &As[rl * APITCH + q * 32];
        #pragma unroll
        for (int i = 0; i < 8; ++i) {
            const float4 v = src[i];
            s16x4 s4;
            s4.x = f2bf(v.x); s4.y = f2bf(v.y);
            s4.z = f2bf(v.z); s4.w = f2bf(v.w);
            *(s16x4*)(dst + i * 4) = s4;
        }
    }
    // --- stage W transposed -> Wt[n][k] bf16 ---
    {
        #pragma unroll
        for (int p = 0; p < 2; ++p) {
            const int k  = p * 64 + (t >> 2);
            const int n0 = (t & 3) * 16;
            const float4* wsrc = (const float4*)(W + (size_t)k * OUT_DIM + n0);
            #pragma unroll
            for (int i = 0; i < 4; ++i) {
                const float4 v = wsrc[i];
                Wt[(n0 + 4 * i + 0) * APITCH + k] = f2bf(v.x);
                Wt[(n0 + 4 * i + 1) * APITCH + k] = f2bf(v.y);
                Wt[(n0 + 4 * i + 2) * APITCH + k] = f2bf(v.z);
                Wt[(n0 + 4 * i + 3) * APITCH + k] = f2bf(v.w);
            }
        }
    }
    __syncthreads();

    const int wave = t >> 6;
    const int lane = t & 63;
    const int m    = lane & 15;
    const int quad = lane >> 4;

    f32x4 acc[4];
    #pragma unroll
    for (int ct = 0; ct < 4; ++ct) acc[ct] = (f32x4){0.f, 0.f, 0.f, 0.f};

    const short* Abase = &As[(wave * 16 + m) * APITCH + quad * 8];
    const short* Bbase = &Wt[m * APITCH + quad * 8];

    #pragma unroll
    for (int kc = 0; kc < 4; ++kc) {
        const s16x8 a = *(const s16x8*)(Abase + kc * 32);
        #pragma unroll
        for (int ct = 0; ct < 4; ++ct) {
            const s16x8 b = *(const s16x8*)(Bbase + ct * 16 * APITCH + kc * 32);
            acc[ct] = __builtin_amdgcn_mfma_f32_16x16x32_bf16(a, b, acc[ct], 0, 0, 0);
        }
    }

    // C/D layout: col = lane&15, row = quad*4 + reg. Scale row by dis_row.
    #pragma unroll
    for (int r = 0; r < 4; ++r) {
        const int grow = r0 + wave * 16 + quad * 4 + r;
        const int gc = min(grow, N - 1);
        const unsigned long long p = packed[gc];
        const float deg = (float)((double)(p & DEGMASK) * (1.0 / FIXSHIFT));
        const float dis = rsqrtf(deg + 1.f);
        if (grow < N) {
            #pragma unroll
            for (int ct = 0; ct < 4; ++ct)
                xps[(size_t)grow * OUT_DIM + ct * 16 + m] =
                    (unsigned short)f2bf(acc[ct][r] * dis);
        }
    }
}

// ---------------------------------------------------------------------------
// scan_a: per-block (1024 items) exclusive scan of counts.
// ---------------------------------------------------------------------------
__global__ __launch_bounds__(256) void scan_a(const unsigned long long* __restrict__ packed,
                                              int* __restrict__ pos,
                                              int* __restrict__ btot,
                                              int N) {
    __shared__ int s[256];
    const int t = threadIdx.x;
    const int i0 = blockIdx.x * 1024 + t * 4;
    int v[4]; int sum = 0;
    #pragma unroll
    for (int j = 0; j < 4; ++j) {
        unsigned long long p = (i0 + j < N) ? packed[i0 + j] : 0ull;
        v[j] = (int)(p >> CNTSHIFT);
        sum += v[j];
    }
    s[t] = sum;
    __syncthreads();
    for (int off = 1; off < 256; off <<= 1) {
        int add = (t >= off) ? s[t - off] : 0;
        __syncthreads();
        s[t] += add;
        __syncthreads();
    }
    int excl = s[t] - sum;
    #pragma unroll
    for (int j = 0; j < 4; ++j) {
        if (i0 + j < N) pos[i0 + j] = excl;
        excl += v[j];
    }
    if (t == 255) btot[blockIdx.x] = s[255];
}

// ---------------------------------------------------------------------------
// scan_b_sigma: single block. Scan btot -> bexcl AND compute inv_sigma.
// ---------------------------------------------------------------------------
__global__ __launch_bounds__(256) void scan_b_sigma(const int* __restrict__ btot,
                                                    const float* __restrict__ W,
                                                    const float* __restrict__ u,
                                                    int* __restrict__ bexcl,
                                                    float* __restrict__ inv_sigma,
                                                    int NB) {
    __shared__ int s[256];
    __shared__ float red[256];
    __shared__ float vsh[OUT_DIM];
    const int t = threadIdx.x;

    const int own = (t < NB) ? btot[t] : 0;
    s[t] = own;
    __syncthreads();
    for (int off = 1; off < 256; off <<= 1) {
        int add = (t >= off) ? s[t - off] : 0;
        __syncthreads();
        s[t] += add;
        __syncthreads();
    }
    if (t < NB) bexcl[t] = s[t] - own;

    {
        const int j = t & 63;
        const int i0 = (t >> 6) * 32;
        float tv = 0.f;
        #pragma unroll 8
        for (int i = 0; i < 32; ++i) tv += W[(i0 + i) * OUT_DIM + j] * u[i0 + i];
        red[t] = tv;
    }
    __syncthreads();
    float tvj = 0.f;
    if (t < 64) tvj = red[t] + red[t + 64] + red[t + 128] + red[t + 192];
    __syncthreads();
    red[t] = (t < 64) ? tvj * tvj : 0.f;
    __syncthreads();
    for (int sr = 128; sr > 0; sr >>= 1) {
        if (t < sr) red[t] += red[t + sr];
        __syncthreads();
    }
    const float nv = sqrtf(red[0]) + 1e-12f;
    __syncthreads();
    if (t < 64) vsh[t] = tvj / nv;
    __syncthreads();
    float wv = 0.f;
    if (t < 128) {
        #pragma unroll 8
        for (int j = 0; j < OUT_DIM; ++j) wv += W[t * OUT_DIM + j] * vsh[j];
    }
    red[t] = (t < 128) ? wv * wv : 0.f;
    __syncthreads();
    for (int sr = 128; sr > 0; sr >>= 1) {
        if (t < sr) red[t] += red[t + sr];
        __syncthreads();
    }
    if (t == 0) {
        const float s2 = red[0];
        const float sn = sqrtf(s2);
        inv_sigma[0] = (sn + 1e-12f) / s2;   // 1/sigma
    }
}

// ---------------------------------------------------------------------------
// permute: spk[p] = (row, w). 1 edge/thread (best-measured).
// ---------------------------------------------------------------------------
__global__ __launch_bounds__(256) void permute(const int* __restrict__ ei,
                                               const float* __restrict__ ew,
                                               const int* __restrict__ pos,
                                               const int* __restrict__ bexcl,
                                               const int* __restrict__ slot,
                                               int2* __restrict__ spk,
                                               int E) {
    const int e = blockIdx.x * 256 + threadIdx.x;
    if (e >= E) return;
    const int row = ei[e];
    const int col = ei[E + e];
    const float w = 1.f / (1.f + expf(-ew[e]));
    const int p = pos[col] + bexcl[col >> 10] + slot[e];
    int2 pk; pk.x = row; pk.y = __float_as_int(w);
    spk[p] = pk;
}

// ---------------------------------------------------------------------------
// gather: half-wave (32 lanes) per node; lane = 2 cols via one uint load.
// 2 nodes per wave; 4-way unrolled segment loop (up to 8 outstanding random
// loads per wave). out = isg*dis_n*(sum xps[row]*w + xps[n]) + bias.
// ---------------------------------------------------------------------------
__global__ __launch_bounds__(256) void gather(const int2* __restrict__ spk,
                                              const int* __restrict__ pos,
                                              const int* __restrict__ bexcl,
                                              const unsigned long long* __restrict__ packed,
                                              const unsigned int* __restrict__ xps32,
                                              const float* __restrict__ bias,
                                              const float* __restrict__ inv_sigma,
                                              float* __restrict__ out,
                                              int N) {
    const int t = threadIdx.x;
    const int wv = t >> 6;          // wave 0..3
    const int half = (t >> 5) & 1;  // half-wave id
    const int hl = t & 31;          // lane within half
    const int n = blockIdx.x * 8 + wv * 2 + half;
    if (n >= N) return;

    const unsigned long long p = packed[n];
    const int c = (int)(p >> CNTSHIFT);
    const float deg = (float)((double)(p & DEGMASK) * (1.0 / FIXSHIFT));
    const int st = pos[n] + bexcl[n >> 10];
    const int end = st + c;

    float accL = 0.f, accH = 0.f;   // cols 2*hl, 2*hl+1
    int j = st;
    for (; j + 3 < end; j += 4) {
        const int2 e0 = spk[j];
        const int2 e1 = spk[j + 1];
        const int2 e2 = spk[j + 2];
        const int2 e3 = spk[j + 3];
        const unsigned int a0 = xps32[(size_t)e0.x * 32 + hl];
        const unsigned int a1 = xps32[(size_t)e1.x * 32 + hl];
        const unsigned int a2 = xps32[(size_t)e2.x * 32 + hl];
        const unsigned int a3 = xps32[(size_t)e3.x * 32 + hl];
        const float w0 = __int_as_float(e0.y);
        const float w1 = __int_as_float(e1.y);
        const float w2 = __int_as_float(e2.y);
        const float w3 = __int_as_float(e3.y);
        accL += bfLo(a0) * w0 + bfLo(a1) * w1 + bfLo(a2) * w2 + bfLo(a3) * w3;
        accH += bfHi(a0) * w0 + bfHi(a1) * w1 + bfHi(a2) * w2 + bfHi(a3) * w3;
    }
    for (; j < end; ++j) {
        const int2 e0 = spk[j];
        const unsigned int a0 = xps32[(size_t)e0.x * 32 + hl];
        const float w0 = __int_as_float(e0.y);
        accL += bfLo(a0) * w0;
        accH += bfHi(a0) * w0;
    }

    const unsigned int selfU = xps32[(size_t)n * 32 + hl];
    const float isg = inv_sigma[0];
    const float sc = isg * rsqrtf(deg + 1.f);
    const float2 bv = ((const float2*)bias)[hl];
    float2 o;
    o.x = sc * (accL + bfLo(selfU)) + bv.x;
    o.y = sc * (accH + bfHi(selfU)) + bv.y;
    ((float2*)out)[(size_t)n * 32 + hl] = o;
}

// ---------------------------------------------------------------------------
extern "C" void kernel_launch(void* const* d_in, const int* in_sizes, int n_in,
                              void* d_out, int out_size, void* d_ws, size_t ws_size,
                              hipStream_t stream) {
    const float* x    = (const float*)d_in[0];
    const int*   ei   = (const int*)d_in[1];
    const float* W    = (const float*)d_in[2];
    const float* bias = (const float*)d_in[3];
    const float* ew   = (const float*)d_in[4];
    const float* u    = (const float*)d_in[5];
    float* out = (float*)d_out;

    const int N = in_sizes[0] / IN_DIM;   // 100000
    const int E = in_sizes[4];            // 600000
    const int NB = (N + 1023) / 1024;     // 98 scan blocks (<=256)
    const int EB = (E + 255) / 256;       // 2344 edge blocks

    char* ws = (char*)d_ws;
    size_t off = 0;
    unsigned long long* packed = (unsigned long long*)(ws + off); off += (size_t)N * 8;
    int*   slot = (int*)  (ws + off); off += (size_t)E * 4;
    int*   pos  = (int*)  (ws + off); off += (size_t)N * 4;
    int*   btot = (int*)  (ws + off); off += 4096;
    int*   bexcl= (int*)  (ws + off); off += 4096;
    float* isg  = (float*)(ws + off); off += 1024;
    int2*  spk  = (int2*) (ws + off); off += (size_t)E * 8;
    unsigned short* xps = (unsigned short*)(ws + off); off += (size_t)N * OUT_DIM * 2;

    hipMemsetAsync(packed, 0, (size_t)N * 8, stream);
    edge_prep<<<EB, 256, 0, stream>>>(ei, ew, packed, slot, E);
    gemm_mfma<<<(N + 63) / 64, 256, 0, stream>>>(x, W, packed, xps, N);
    scan_a<<<NB, 256, 0, stream>>>(packed, pos, btot, N);
    scan_b_sigma<<<1, 256, 0, stream>>>(btot, W, u, bexcl, isg, NB);
    permute<<<EB, 256, 0, stream>>>(ei, ew, pos, bexcl, slot, spk, E);
    gather<<<(N + 7) / 8, 256, 0, stream>>>(spk, pos, bexcl, packed,
                                            (const unsigned int*)xps, bias, isg, out, N);
}